// Round 3
// baseline (725.385 us; speedup 1.0000x reference)
//
#include <hip/hip_runtime.h>
#include <stdint.h>

#define B_ 4
#define N_ 4096
#define C1_ 58
#define K_ 32
#define EPS_ 1e-5f
#define PPB 16   // points per block (processed 2 at a time by 4 waves)

typedef __attribute__((ext_vector_type(8))) short bf16x8;
typedef __attribute__((ext_vector_type(4))) float f32x4;

static __device__ __forceinline__ float bf2f(unsigned short u){
  return __uint_as_float(((unsigned int)u) << 16);
}
static __device__ __forceinline__ unsigned short f2bf(float f){
  unsigned int x = __float_as_uint(f);
  x = (x + 0x7FFFu + ((x >> 16) & 1u)) >> 16;
  return (unsigned short)x;
}

// ---------------- ball query (wave-parallel) ----------------
__global__ __launch_bounds__(256) void ball_kernel(const float* __restrict__ xyz,
                                                   int* __restrict__ inds){
  const int wid  = (blockIdx.x * 256 + threadIdx.x) >> 6;   // query id over B*N
  const int lane = threadIdx.x & 63;
  const int b = wid >> 12;
  const int n = wid & (N_ - 1);
  const float* xb = xyz + (size_t)b * N_ * 3;
  const float qx = xb[n*3+0], qy = xb[n*3+1], qz = xb[n*3+2];
  const float R2 = (float)(0.3 * 0.3);
  int* outp = inds + (size_t)wid * K_;
  int cnt = 0;
  int first = -1;
  for (int j0 = 0; j0 < N_ && cnt < K_; j0 += 64){
    const int j = j0 + lane;
    float dx = xb[j*3+0] - qx;
    float dy = xb[j*3+1] - qy;
    float dz = xb[j*3+2] - qz;
    float s = __fadd_rn(__fadd_rn(__fmul_rn(dx,dx), __fmul_rn(dy,dy)), __fmul_rn(dz,dz));
    bool p = (s <= R2);
    unsigned long long mask = __ballot(p);
    if (p){
      int pos = cnt + __popcll(mask & ((1ull << lane) - 1ull));
      if (pos < K_) outp[pos] = j;
    }
    if (first < 0 && mask) first = j0 + __builtin_ctzll(mask);
    cnt += __popcll(mask);
  }
  if (lane < K_ && lane >= cnt) outp[lane] = first;
}

// ---------------- MFMA conv layer ----------------
// MODE_IN : 0 = gather new_points -> LDS staging, 1 = global bf16 + GN(sc,sb)+relu
// MODE_OUT: 0 = store raw bf16 Y + group stats
//           2 = group stats + per-point max/min over k -> ymax/ymin [b][n][128]
template<int COUT, int MODE_IN, int MODE_OUT>
__global__ __launch_bounds__(256)
void conv_mfma(const float* __restrict__ feature, const float* __restrict__ xyz,
               const int* __restrict__ inds,
               const unsigned short* __restrict__ xin,
               const float* __restrict__ scin, const float* __restrict__ sbin,
               const float* __restrict__ Wg,
               unsigned short* __restrict__ xout, float* __restrict__ sums,
               float* __restrict__ ymax, float* __restrict__ ymin)
{
  constexpr int NT = COUT / 16;
  __shared__ unsigned short Wl[COUT * 64];                  // bf16, chunk-XOR-swizzled
  __shared__ unsigned short Xl[(MODE_IN==0) ? 2*32*64 : 8]; // 2 points staging
  __shared__ int sidx[(MODE_IN==0) ? 2*K_ : 1];
  __shared__ float redmx[(MODE_OUT==2) ? 2*128 : 1];
  __shared__ float redmn[(MODE_OUT==2) ? 2*128 : 1];

  const int t = threadIdx.x;
  const int b = blockIdx.y;
  const int n0 = blockIdx.x * PPB;
  const int lane = t & 63;
  const int w = t >> 6;
  const int col = lane & 15;
  const int quad = lane >> 4;
  const int p_loc = w >> 1;     // which of 2 in-flight points
  const int mt = w & 1;         // M-tile (k rows 0-15 / 16-31)

  // ---- stage W: f32 global -> bf16 LDS, 16B chunk c stored at c^(ch&7) ----
  for (int i = t; i < COUT * 8; i += 256){
    int ch = i >> 3, c = i & 7;
    const float* wr = Wg + ch * 64 + c * 8;
    bf16x8 v;
    #pragma unroll
    for (int j = 0; j < 8; ++j) v[j] = (short)f2bf(wr[j]);
    *(bf16x8*)&Wl[ch * 64 + ((c ^ (ch & 7)) * 8)] = v;
  }

  // ---- per-lane input-channel GN scale/bias (MODE_IN==1) ----
  float sc[16], sb[16];
  if constexpr (MODE_IN == 1){
    #pragma unroll
    for (int kt = 0; kt < 2; ++kt){
      const float* scp = scin + b * 64 + kt * 32 + quad * 8;
      const float* sbp = sbin + b * 64 + kt * 32 + quad * 8;
      #pragma unroll
      for (int j = 0; j < 8; ++j){ sc[kt*8+j] = scp[j]; sb[kt*8+j] = sbp[j]; }
    }
  }
  __syncthreads();

  float s0=0.f,q0=0.f,s1=0.f,q1=0.f,s2=0.f,q2=0.f,s3=0.f,q3=0.f;

  for (int r = 0; r < PPB/2; ++r){
    const int n = n0 + r*2 + p_loc;
    const size_t pt = (size_t)b * N_ + n;
    const size_t row0 = pt * K_ + (size_t)mt * 16;

    bf16x8 afrag[2];

    if constexpr (MODE_IN == 0){
      __syncthreads();   // previous round's Xl reads done
      if (t < 2*K_)
        sidx[t] = inds[((size_t)b*N_ + n0 + r*2 + (t>>5)) * K_ + (t & 31)];
      __syncthreads();
      for (int i = t; i < 512; i += 256){
        int pl = i >> 8, rem = i & 255, row = rem >> 3, c = rem & 7;
        int nn = n0 + r*2 + pl;
        size_t base = (size_t)b * N_ + nn;
        float cx = xyz[base*3+0], cy = xyz[base*3+1], cz = xyz[base*3+2];
        int idx = sidx[pl*K_ + row];
        size_t nb = (size_t)b * N_ + idx;
        const float* frow = feature + nb * C1_;
        bf16x8 vv;
        #pragma unroll
        for (int j = 0; j < 8; ++j){
          int c0 = c*8 + j;
          float val;
          if (c0 < 3){
            val = (c0 == 0) ? cx : ((c0 == 1) ? cy : cz);
          } else if (c0 < 6){
            float nc = xyz[nb*3 + (c0-3)];
            float cc = (c0 == 3) ? cx : ((c0 == 4) ? cy : cz);
            val = nc - cc;
          } else {
            val = frow[c0 - 6];
          }
          vv[j] = (short)f2bf(val);
        }
        *(bf16x8*)&Xl[pl*2048 + row*64 + ((c ^ (row & 7)) * 8)] = vv;
      }
      __syncthreads();
      #pragma unroll
      for (int kt = 0; kt < 2; ++kt){
        int rowl = mt*16 + col;
        int c = kt*4 + quad;
        afrag[kt] = *(const bf16x8*)&Xl[p_loc*2048 + rowl*64 + ((c ^ (rowl & 7)) * 8)];
      }
    } else {
      #pragma unroll
      for (int kt = 0; kt < 2; ++kt){
        const unsigned short* src = xin + (row0 + col) * 64 + kt*32 + quad*8;
        uint4 raw = *(const uint4*)src;
        const unsigned short* u = (const unsigned short*)&raw;
        bf16x8 a;
        #pragma unroll
        for (int j = 0; j < 8; ++j){
          float x = bf2f(u[j]);
          float y = fmaf(x, sc[kt*8+j], sb[kt*8+j]);
          y = fmaxf(y, 0.f);
          a[j] = (short)f2bf(y);
        }
        afrag[kt] = a;
      }
    }

    // ---- MFMA: acc[nt] += A(16x32) * B(32x16) over 2 k-tiles ----
    f32x4 acc[NT];
    #pragma unroll
    for (int nt = 0; nt < NT; ++nt) acc[nt] = (f32x4){0.f,0.f,0.f,0.f};
    #pragma unroll
    for (int kt = 0; kt < 2; ++kt){
      #pragma unroll
      for (int nt = 0; nt < NT; ++nt){
        int ch = nt*16 + col;
        int c = kt*4 + quad;
        bf16x8 bfrag = *(const bf16x8*)&Wl[ch*64 + ((c ^ (ch & 7)) * 8)];
        acc[nt] = __builtin_amdgcn_mfma_f32_16x16x32_bf16(afrag[kt], bfrag, acc[nt], 0, 0, 0);
      }
    }

    // ---- group stats on raw y ----
    #pragma unroll
    for (int nt = 0; nt < NT; ++nt){
      #pragma unroll
      for (int rg = 0; rg < 4; ++rg){
        float y = acc[nt][rg];
        if constexpr (COUT == 64){
          if (nt < 2){ s0 += y; q0 = fmaf(y,y,q0); } else { s1 += y; q1 = fmaf(y,y,q1); }
        } else {
          if      (nt < 2){ s0 += y; q0 = fmaf(y,y,q0); }
          else if (nt < 4){ s1 += y; q1 = fmaf(y,y,q1); }
          else if (nt < 6){ s2 += y; q2 = fmaf(y,y,q2); }
          else            { s3 += y; q3 = fmaf(y,y,q3); }
        }
      }
    }

    if constexpr (MODE_OUT == 0){
      // direct bf16 stores (L2 merges the 32B row chunks)
      #pragma unroll
      for (int nt = 0; nt < NT; ++nt){
        #pragma unroll
        for (int rg = 0; rg < 4; ++rg){
          size_t row = row0 + quad*4 + rg;
          xout[row * COUT + nt*16 + col] = f2bf(acc[nt][rg]);
        }
      }
    } else {
      // per-point raw-y max/min over the 32 k rows
      float cmx[NT], cmn[NT];
      #pragma unroll
      for (int nt = 0; nt < NT; ++nt){
        cmx[nt] = fmaxf(fmaxf(acc[nt][0], acc[nt][1]), fmaxf(acc[nt][2], acc[nt][3]));
        cmn[nt] = fminf(fminf(acc[nt][0], acc[nt][1]), fminf(acc[nt][2], acc[nt][3]));
      }
      #pragma unroll
      for (int nt = 0; nt < NT; ++nt){
        cmx[nt] = fmaxf(cmx[nt], __shfl_xor(cmx[nt], 16, 64));
        cmx[nt] = fmaxf(cmx[nt], __shfl_xor(cmx[nt], 32, 64));
        cmn[nt] = fminf(cmn[nt], __shfl_xor(cmn[nt], 16, 64));
        cmn[nt] = fminf(cmn[nt], __shfl_xor(cmn[nt], 32, 64));
      }
      if (mt == 0 && lane < 16){
        #pragma unroll
        for (int nt = 0; nt < NT; ++nt){
          redmx[p_loc*128 + nt*16 + lane] = cmx[nt];
          redmn[p_loc*128 + nt*16 + lane] = cmn[nt];
        }
      }
      __syncthreads();
      if (mt == 1){
        #pragma unroll
        for (int nt = 0; nt < NT; ++nt){
          cmx[nt] = fmaxf(cmx[nt], redmx[p_loc*128 + nt*16 + col]);
          cmn[nt] = fminf(cmn[nt], redmn[p_loc*128 + nt*16 + col]);
        }
        float vx0 = (quad==0)?cmx[0]:(quad==1)?cmx[1]:(quad==2)?cmx[2]:cmx[3];
        float vx1 = (quad==0)?cmx[4]:(quad==1)?cmx[5]:(quad==2)?cmx[6]:cmx[7];
        float vn0 = (quad==0)?cmn[0]:(quad==1)?cmn[1]:(quad==2)?cmn[2]:cmn[3];
        float vn1 = (quad==0)?cmn[4]:(quad==1)?cmn[5]:(quad==2)?cmn[6]:cmn[7];
        float* ym = ymax + pt * 128;
        float* yn = ymin + pt * 128;
        ym[lane] = vx0; ym[64 + lane] = vx1;
        yn[lane] = vn0; yn[64 + lane] = vn1;
      }
      __syncthreads();   // redmx reuse next round
    }
  }

  // ---- epilogue: reduce stats across 64 lanes, atomic per group ----
  #pragma unroll
  for (int off = 32; off > 0; off >>= 1){
    s0 += __shfl_down(s0, off, 64); q0 += __shfl_down(q0, off, 64);
    s1 += __shfl_down(s1, off, 64); q1 += __shfl_down(q1, off, 64);
    if constexpr (COUT == 128){
      s2 += __shfl_down(s2, off, 64); q2 += __shfl_down(q2, off, 64);
      s3 += __shfl_down(s3, off, 64); q3 += __shfl_down(q3, off, 64);
    }
  }
  if (lane == 0){
    atomicAdd(&sums[(b*4+0)*2+0], s0); atomicAdd(&sums[(b*4+0)*2+1], q0);
    atomicAdd(&sums[(b*4+1)*2+0], s1); atomicAdd(&sums[(b*4+1)*2+1], q1);
    if constexpr (COUT == 128){
      atomicAdd(&sums[(b*4+2)*2+0], s2); atomicAdd(&sums[(b*4+2)*2+1], q2);
      atomicAdd(&sums[(b*4+3)*2+0], s3); atomicAdd(&sums[(b*4+3)*2+1], q3);
    }
  }
}

// ---------------- stats finalize: fold GN affine into per-(b,ch) scale/bias ----
__global__ void finalize_kernel(const float* __restrict__ sums,
                                const float* __restrict__ g, const float* __restrict__ bb,
                                float* __restrict__ sc, float* __restrict__ sb, int nch){
  int t = blockIdx.x * blockDim.x + threadIdx.x;
  if (t >= 4 * nch) return;
  int b = t / nch, c = t % nch;
  int grp = c >> 5;
  const float cnt = 4194304.f;   // 32 ch * K * N
  float s = sums[(b*4+grp)*2+0], s2v = sums[(b*4+grp)*2+1];
  float mean = s / cnt;
  float var = s2v / cnt - mean * mean;
  float rstd = 1.f / sqrtf(var + EPS_);
  float scale = rstd * g[c];
  sc[b*nch + c] = scale;
  sb[b*nch + c] = bb[c] - mean * scale;
}

// ---------------- final: GN2+relu on k-extremum, transpose [b][n][128]->[b][128][n] ----
__global__ __launch_bounds__(256)
void out_kernel(const float* __restrict__ ymax, const float* __restrict__ ymin,
                const float* __restrict__ sc2, const float* __restrict__ sb2,
                float* __restrict__ out){
  __shared__ float tile[64 * 129];
  const int t = threadIdx.x;
  const int b = blockIdx.y;
  const int n0 = blockIdx.x * 64;
  const float4* mx4 = (const float4*)(ymax + ((size_t)b * N_ + n0) * 128);
  const float4* mn4 = (const float4*)(ymin + ((size_t)b * N_ + n0) * 128);
  #pragma unroll
  for (int i = 0; i < 8; ++i){
    int e4 = i * 256 + t;            // float4 idx; 32 per n-row
    int nl = e4 >> 5;
    int ch0 = (e4 & 31) * 4;
    float4 vx = mx4[e4], vn = mn4[e4];
    #pragma unroll
    for (int j = 0; j < 4; ++j){
      float slope = sc2[b*128 + ch0 + j];
      float off   = sb2[b*128 + ch0 + j];
      float y = (slope >= 0.f) ? ((const float*)&vx)[j] : ((const float*)&vn)[j];
      float v = fmaf(y, slope, off);
      tile[nl*129 + ch0 + j] = v > 0.f ? v : 0.f;
    }
  }
  __syncthreads();
  const int ch = t >> 1, h = t & 1;
  float* orow = out + ((size_t)b * 128 + ch) * N_ + n0 + h * 32;
  #pragma unroll
  for (int jj = 0; jj < 8; ++jj){
    float4 v;
    #pragma unroll
    for (int c = 0; c < 4; ++c)
      ((float*)&v)[c] = tile[(h*32 + jj*4 + c)*129 + ch];
    ((float4*)orow)[jj] = v;
  }
}

extern "C" void kernel_launch(void* const* d_in, const int* in_sizes, int n_in,
                              void* d_out, int out_size, void* d_ws, size_t ws_size,
                              hipStream_t stream) {
  const float* feature = (const float*)d_in[0];
  const float* xyz     = (const float*)d_in[1];
  const float* W0 = (const float*)d_in[2];
  const float* g0 = (const float*)d_in[3];
  const float* b0 = (const float*)d_in[4];
  const float* W1 = (const float*)d_in[5];
  const float* g1 = (const float*)d_in[6];
  const float* b1 = (const float*)d_in[7];
  const float* W2 = (const float*)d_in[8];
  const float* g2 = (const float*)d_in[9];
  const float* b2 = (const float*)d_in[10];
  float* out = (float*)d_out;

  char* ws = (char*)d_ws;
  const size_t INDS_BYTES = (size_t)B_ * N_ * K_ * sizeof(int);   // 2 MiB
  const size_t XBYTES     = (size_t)B_ * N_ * K_ * 64 * 2;        // 64 MiB each
  const size_t YBYTES     = (size_t)B_ * N_ * 128 * sizeof(float);// 8 MiB each
  int* inds           = (int*)ws;
  unsigned short* x1  = (unsigned short*)(ws + INDS_BYTES);          // [2,66) MiB
  unsigned short* x0  = (unsigned short*)(ws + INDS_BYTES + XBYTES); // [66,130) MiB
  float* ymax         = (float*)(ws + INDS_BYTES + XBYTES);          // overlays dead x0
  float* ymin         = (float*)(ws + INDS_BYTES + XBYTES + YBYTES);
  float* sums         = (float*)(ws + INDS_BYTES + 2 * XBYTES);      // [3][B][4][2]
  float* sc0 = sums + 96;          // [4][64]
  float* sb0 = sc0 + 256;
  float* sc1 = sb0 + 256;
  float* sb1 = sc1 + 256;
  float* sc2 = sb1 + 256;          // [4][128]
  float* sb2 = sc2 + 512;

  hipMemsetAsync(sums, 0, 96 * sizeof(float), stream);

  ball_kernel<<<B_ * N_ / 4, 256, 0, stream>>>(xyz, inds);

  dim3 cgrid(N_ / PPB, B_);

  // layer 0: gather -> MFMA -> raw bf16 x0 + stats
  conv_mfma<64, 0, 0><<<cgrid, 256, 0, stream>>>(
      feature, xyz, inds, nullptr, nullptr, nullptr,
      W0, x0, sums + 0, nullptr, nullptr);
  finalize_kernel<<<1, 256, 0, stream>>>(sums + 0, g0, b0, sc0, sb0, 64);

  // layer 1: GN0+relu(x0) -> MFMA -> raw bf16 x1 + stats
  conv_mfma<64, 1, 0><<<cgrid, 256, 0, stream>>>(
      nullptr, nullptr, nullptr, x0, sc0, sb0,
      W1, x1, sums + 32, nullptr, nullptr);
  finalize_kernel<<<1, 256, 0, stream>>>(sums + 32, g1, b1, sc1, sb1, 64);

  // layer 2: GN1+relu(x1) -> MFMA -> stats + max/min over k
  conv_mfma<128, 1, 2><<<cgrid, 256, 0, stream>>>(
      nullptr, nullptr, nullptr, x1, sc1, sb1,
      W2, nullptr, sums + 64, ymax, ymin);
  finalize_kernel<<<2, 256, 0, stream>>>(sums + 64, g2, b2, sc2, sb2, 128);

  // final: GN2+relu on extremum + transpose to [b][128][n]
  dim3 ogrid(N_ / 64, B_);
  out_kernel<<<ogrid, 256, 0, stream>>>(ymax, ymin, sc2, sb2, out);
}